// Round 7
// baseline (252.663 us; speedup 1.0000x reference)
//
#include <hip/hip_runtime.h>
#include <hip/hip_bf16.h>

// ---------- types / helpers ----------
typedef __attribute__((ext_vector_type(8))) short short8;     // 8 bf16 = 4 VGPRs (MFMA A/B frag)
typedef __attribute__((ext_vector_type(4))) float f32x4;      // MFMA C/D frag

__device__ __forceinline__ float bf2f(unsigned short s) {
    union { unsigned int u; float f; } v; v.u = ((unsigned int)s) << 16; return v.f;
}
__device__ __forceinline__ unsigned short f2bf(float f) {  // round-to-nearest-even
    union { float f; unsigned int u; } v; v.f = f;
    unsigned int u = v.u;
    unsigned int r = (u + 0x7FFFu + ((u >> 16) & 1u)) >> 16;
    return (unsigned short)r;
}
__device__ __forceinline__ void gload_lds16(const void* g, void* l) {
    // async global->LDS, 16B/lane; LDS dest = wave-uniform base + lane*16
    __builtin_amdgcn_global_load_lds((const __attribute__((address_space(1))) void*)g,
                                     (__attribute__((address_space(3))) void*)l, 16, 0, 0);
}

// ---------- constants ----------
#define BATCH 256
#define CHAN  768
#define HW    196
#define SPS   196
#define HID   512
#define MROWS 50176   // BATCH*SPS
#define K1    1536    // 2*CHAN

// 8-phase GEMM geometry: BM=BN=256, BK=64; 8 waves (2M x 4N), per-wave 128x64 (acc[8][4]).
// LDS 160KB exactly: A triple-buffered (3 x 32KB, slots t%3) + B double-buffered
// (2 x 32KB, slots t&1) at offset 98304.  Every phase reads ALL halves of tile t
// (reads are wave-partitioned, NOT phase-partitioned) -> tile t must be FULLY resident
// at its ph1; achieved by prefetch distance 2 for A (HBM, slow) and 1 for B (L2-hot).
#define ASLOT 32768
#define HHALF 16384
#define BOFF  98304

// ---------- weight prep ----------
// in [K][N] fp32 -> out [N][K] bf16  (N-major so B-frag reads are contiguous)
__global__ void transpose_cast(const float* __restrict__ in, unsigned short* __restrict__ out,
                               int K, int N) {
    int idx = blockIdx.x * 256 + threadIdx.x;
    if (idx >= K * N) return;
    int n = idx / K, k = idx - n * K;
    out[idx] = f2bf(in[(size_t)k * N + n]);
}

// ---------- gather + out-init: feats bf16; out[0:2M)=b3 (pred init); out[2M:4M)=deltaxy ----------
__global__ __launch_bounds__(256) void gather_feats(const float* __restrict__ x,
                                                    const int* __restrict__ pxs,
                                                    const int* __restrict__ pys,
                                                    const float* __restrict__ b3,
                                                    unsigned short* __restrict__ feats,
                                                    float* __restrict__ out) {
    __shared__ float lds[64 * 197];   // pitch 197: stride-5 banks, conflict-free
    int chunk = blockIdx.x;           // 0..11 (64-channel chunk)
    int b     = blockIdx.y;           // 0..255
    int c0 = chunk * 64;
    const float* xb = x + ((size_t)b * CHAN + c0) * HW;
    for (int t = threadIdx.x; t < 64 * HW; t += 256) {
        int j = t / HW, p = t - j * HW;
        lds[j * 197 + p] = xb[t];     // coalesced read of 64 full channels
    }
    if (chunk == 0) {                 // per-batch: init pred rows to b3, write deltaxy
        float b30 = b3[0], b31 = b3[1];
        for (int i = threadIdx.x; i < SPS * 2; i += 256) {
            int idx = b * SPS * 2 + i;
            out[idx] = (i & 1) ? b31 : b30;                          // pred init (atomics add on top)
            out[MROWS * 2 + idx] = (float)(pxs[idx] - pys[idx]) + 13.0f;  // (H-1)=13
        }
    }
    __syncthreads();
    int w = threadIdx.x >> 6, lane = threadIdx.x & 63;
    for (int s = w; s < SPS; s += 4) {
        int base = (b * SPS + s) * 2;
        int ix = pxs[base] * 14 + pxs[base + 1];
        int iy = pys[base] * 14 + pys[base + 1];
        size_t ro = (size_t)(b * SPS + s) * K1;
        feats[ro + c0 + lane]        = f2bf(lds[lane * 197 + ix]);  // 128B coalesced store
        feats[ro + CHAN + c0 + lane] = f2bf(lds[lane * 197 + iy]);
    }
}

// ---------- 256x256 bf16 MFMA GEMM, 8-phase + counted vmcnt (T3+T4), T2, T5 ----------
// C = relu(A @ Bt^T + bias); A[M][K], Bt[N=512][K] row-major bf16.
// Grid 1-D: bid -> (mTile = bid>>1, nTile = bid&1).
// Schedule per K-tile t (4 phases, 2 barriers each):
//   ph1: ds_reads(B kk0, A mh0 kk0) | stage B(t+1)h0 | bar | 16-MFMA | bar
//   ph2: ds_reads(A mh1 kk0)        | stage B(t+1)h1 | bar | 16-MFMA | bar
//   ph3: ds_reads(B kk1, A mh0 kk1) | stage A(t+2)h0 | bar | 16-MFMA | bar
//   ph4: ds_reads(A mh1 kk1)        | stage A(t+2)h1 | bar | 16-MFMA | vmcnt(4) | bar
// Ledger (in-order vmem retire): at ph4(t) outstanding = A(t+1)[4 leftover] +
// B(t+1)[4] + A(t+2)[4]; vmcnt(4) retires A(t+1),B(t+1) (both read from ph1(t+1))
// and leaves A(t+2) in flight (retired by ph4(t+1)'s wait -> ~6-phase HBM cover).
// Tail: clamped data index staged into slots no remaining tile reads; vmcnt(0) after loop.
// LDS half layout: slot(hrow, c16) holds global chunk c16 ^ (hrow&7)  [T2 swizzle]
// predMode: accumulate pred = relu(C)@W3 into out via atomics (bias=b2) instead of storing C.
__global__ __launch_bounds__(512, 2) void gemm8p(const unsigned short* __restrict__ A,
                                                 const unsigned short* __restrict__ Bt,
                                                 const float* __restrict__ bias,
                                                 unsigned short* __restrict__ C,
                                                 const float* __restrict__ W3,
                                                 float* __restrict__ out,
                                                 int Kd, int predMode) {
    extern __shared__ char smem[];    // 163840 B = 160KB exactly
    const int t = threadIdx.x;
    const int wid = t >> 6, lane = t & 63;
    const int wr = wid >> 2, wcn = wid & 3;      // 2M x 4N waves; wave owns 128 rows x 64 cols
    const int lr = lane & 15, lk = lane >> 4;
    const int mBase = (blockIdx.x >> 1) * 256;
    const int nBase = (blockIdx.x & 1) * 256;
    const int nK = Kd >> 6;
    f32x4 acc[8][4] = {};

    // stage half h of A K-tile (data tile td, dest slot ts%3); 2 loads/thread
    auto stageA = [&](int ts, int td, int h) {
        char* dst = smem + (ts % 3) * ASLOT + h * HHALF;
        int rbase = mBase + h * 128;
        int k0 = td << 6;
        #pragma unroll
        for (int i = 0; i < 2; ++i) {
            int lin = i * 512 + t;
            int row = lin >> 3;                  // half-local row 0..127
            int cs  = (lin & 7) ^ (row & 7);     // inverse-swizzled source chunk
            gload_lds16((const char*)(A + ((size_t)(rbase + row) * Kd + k0 + cs * 8)),
                        dst + lin * 16);
        }
    };
    auto stageB = [&](int ts, int td, int h) {
        char* dst = smem + BOFF + (ts & 1) * ASLOT + h * HHALF;
        int rbase = nBase + h * 128;
        int k0 = td << 6;
        #pragma unroll
        for (int i = 0; i < 2; ++i) {
            int lin = i * 512 + t;
            int row = lin >> 3;
            int cs  = (lin & 7) ^ (row & 7);
            gload_lds16((const char*)(Bt + ((size_t)(rbase + row) * Kd + k0 + cs * 8)),
                        dst + lin * 16);
        }
    };
    auto readA = [&](int tt, int mi, int kk) -> short8 {   // mi 0..7
        int ra = wr * 128 + mi * 16 + lr;                  // 0..255
        const unsigned short* base = (const unsigned short*)(smem + (tt % 3) * ASLOT);
        return *(const short8*)(base + (ra >> 7) * 8192 + (ra & 127) * 64 + (((kk * 4 + lk) ^ (ra & 7)) * 8));
    };
    auto readB = [&](int tt, int n, int kk) -> short8 {
        int rb = wcn * 64 + n * 16 + lr;                   // 0..255
        const unsigned short* base = (const unsigned short*)(smem + BOFF + (tt & 1) * ASLOT);
        return *(const short8*)(base + (rb >> 7) * 8192 + (rb & 127) * 64 + (((kk * 4 + lk) ^ (rb & 7)) * 8));
    };
    auto doQuad = [&](int mh, short8 (&af)[4], short8 (&bf)[4]) {   // 16-MFMA cluster (T5)
        __builtin_amdgcn_s_setprio(1);
        #pragma unroll
        for (int m = 0; m < 4; ++m)
            #pragma unroll
            for (int n = 0; n < 4; ++n)
                acc[mh * 4 + m][n] = __builtin_amdgcn_mfma_f32_16x16x32_bf16(af[m], bf[n], acc[mh * 4 + m][n], 0, 0, 0);
        __builtin_amdgcn_s_setprio(0);
    };

    // prologue: A(0), A(1), B(0) staged + fully drained
    stageA(0, 0, 0); stageA(0, 0, 1);
    stageA(1, 1, 0); stageA(1, 1, 1);
    stageB(0, 0, 0); stageB(0, 0, 1);
    asm volatile("s_waitcnt vmcnt(0)" ::: "memory");
    __builtin_amdgcn_s_barrier();

    for (int tt = 0; tt < nK; ++tt) {
        int tB = (tt + 1 < nK) ? tt + 1 : nK - 1;   // clamped data tile; dest slot (tt+1)&1 unread when clamped
        int tA = (tt + 2 < nK) ? tt + 2 : nK - 1;   // dest slot (tt+2)%3 unread when clamped
        short8 af[4], bfr[4];
        // ---- ph1: kk0, mh0 ----
        #pragma unroll
        for (int n = 0; n < 4; ++n) bfr[n] = readB(tt, n, 0);
        #pragma unroll
        for (int m = 0; m < 4; ++m) af[m] = readA(tt, m, 0);
        stageB(tt + 1, tB, 0);
        __builtin_amdgcn_s_barrier();
        doQuad(0, af, bfr);
        __builtin_amdgcn_s_barrier();
        // ---- ph2: kk0, mh1 ---- (B frags reused)
        #pragma unroll
        for (int m = 0; m < 4; ++m) af[m] = readA(tt, m + 4, 0);
        stageB(tt + 1, tB, 1);
        __builtin_amdgcn_s_barrier();
        doQuad(1, af, bfr);
        __builtin_amdgcn_s_barrier();
        // ---- ph3: kk1, mh0 ----
        #pragma unroll
        for (int n = 0; n < 4; ++n) bfr[n] = readB(tt, n, 1);
        #pragma unroll
        for (int m = 0; m < 4; ++m) af[m] = readA(tt, m, 1);
        stageA(tt + 2, tA, 0);
        __builtin_amdgcn_s_barrier();
        doQuad(0, af, bfr);
        __builtin_amdgcn_s_barrier();
        // ---- ph4: kk1, mh1 ----
        #pragma unroll
        for (int m = 0; m < 4; ++m) af[m] = readA(tt, m + 4, 1);
        stageA(tt + 2, tA, 1);
        __builtin_amdgcn_s_barrier();
        doQuad(1, af, bfr);
        asm volatile("s_waitcnt vmcnt(4)" ::: "memory");   // A(t+1)+B(t+1) resident; A(t+2) flies
        __builtin_amdgcn_s_barrier();
    }
    asm volatile("s_waitcnt vmcnt(0)" ::: "memory");       // drain tail clamp-stages before exit

    if (!predMode) {
        // epilogue: bias + relu + bf16 store.  C row=(lane>>4)*4+j, col=lane&15 (m89-verified)
        #pragma unroll
        for (int n = 0; n < 4; ++n) {
            int c = nBase + wcn * 64 + n * 16 + lr;
            float bv = bias[c];
            #pragma unroll
            for (int m = 0; m < 8; ++m) {
                int r0 = mBase + wr * 128 + m * 16 + lk * 4;
                #pragma unroll
                for (int j = 0; j < 4; ++j)
                    C[(size_t)(r0 + j) * HID + c] = f2bf(fmaxf(acc[m][n][j] + bv, 0.f));
            }
        }
    } else {
        // fused final layer: pred[r][o] += sum_c relu(acc+b2)[r][c] * W3[c][o]
        float w3v[4][2], bv[4];
        #pragma unroll
        for (int n = 0; n < 4; ++n) {
            int c = nBase + wcn * 64 + n * 16 + lr;
            w3v[n][0] = W3[c * 2 + 0];
            w3v[n][1] = W3[c * 2 + 1];
            bv[n] = bias[c];
        }
        #pragma unroll
        for (int m = 0; m < 8; ++m) {
            #pragma unroll
            for (int j = 0; j < 4; ++j) {
                float p0 = 0.f, p1 = 0.f;
                #pragma unroll
                for (int n = 0; n < 4; ++n) {
                    float v = fmaxf(acc[m][n][j] + bv[n], 0.f);
                    p0 += v * w3v[n][0];
                    p1 += v * w3v[n][1];
                }
                #pragma unroll
                for (int msk = 1; msk < 16; msk <<= 1) {   // reduce over the 16 lr-lanes (same row)
                    p0 += __shfl_xor(p0, msk);
                    p1 += __shfl_xor(p1, msk);
                }
                if (lr == 0) {
                    int r = mBase + wr * 128 + m * 16 + lk * 4 + j;
                    atomicAdd(&out[r * 2 + 0], p0);   // 8 wave-partials per row (2 nTiles x 4 wcn)
                    atomicAdd(&out[r * 2 + 1], p1);
                }
            }
        }
    }
}

// ---------- launch ----------
extern "C" void kernel_launch(void* const* d_in, const int* in_sizes, int n_in,
                              void* d_out, int out_size, void* d_ws, size_t ws_size,
                              hipStream_t stream) {
    const float* x  = (const float*)d_in[0];
    const float* W1 = (const float*)d_in[1];
    const float* b1 = (const float*)d_in[2];
    const float* W2 = (const float*)d_in[3];
    const float* b2 = (const float*)d_in[4];
    const float* W3 = (const float*)d_in[5];
    const float* b3 = (const float*)d_in[6];
    const int*  pxs = (const int*)d_in[7];
    const int*  pys = (const int*)d_in[8];
    float* out = (float*)d_out;
    char* ws = (char*)d_ws;

    // ws layout (bytes)
    unsigned short* W1t   = (unsigned short*)(ws + 0);          // 512x1536 bf16 = 1,572,864
    unsigned short* W2t   = (unsigned short*)(ws + 1572864);    // 512x512  bf16 =   524,288
    unsigned short* h1    = (unsigned short*)(ws + 2099200);    // 50176x512 bf16 = 51,380,224
    unsigned short* feats = (unsigned short*)(ws + 53479424);   // 50176x1536 bf16 = 154,140,672

    // allow 160KB dynamic LDS (attribute set is not a stream op; safe under capture)
    hipFuncSetAttribute((const void*)gemm8p,
                        hipFuncAttributeMaxDynamicSharedMemorySize, 163840);

    transpose_cast<<<(K1 * HID + 255) / 256, 256, 0, stream>>>(W1, W1t, K1, HID);
    transpose_cast<<<(HID * HID + 255) / 256, 256, 0, stream>>>(W2, W2t, HID, HID);
    // gather also initializes out: pred rows = b3 (GEMM2 atomics accumulate), deltaxy written
    gather_feats<<<dim3(12, BATCH), 256, 0, stream>>>(x, pxs, pys, b3, feats, out);
    // GEMM1: h1 = relu(feats @ W1t^T + b1)   grid = 196 mTiles * 2 nTiles = 392
    gemm8p<<<(MROWS / 256) * 2, 512, 163840, stream>>>(
        feats, W1t, b1, h1, nullptr, nullptr, K1, 0);
    // GEMM2 (+fused GEMM3): out[0:2M) += relu(h1 @ W2t^T + b2) @ W3
    gemm8p<<<(MROWS / 256) * 2, 512, 163840, stream>>>(
        h1, W2t, b2, nullptr, W3, out, HID, 1);
}